// Round 11
// baseline (10.242 us; speedup 1.0000x reference)
//
#include <hip/hip_runtime.h>

#define NN 128

typedef __attribute__((ext_vector_type(8))) short short8;
typedef __attribute__((ext_vector_type(4))) float f32x4;

// XOR-swizzled LDS index (units = shorts) for row-major [rows][128] bf16.
// Flips the 16B granule by row&7 -> column-slice ds_read_b128 across 16 rows
// hits all 32 banks at 2-way max (free). Bits <3 untouched -> 8/16B alignment kept.
__device__ __forceinline__ int SWZ(int r, int cs) {
    return (r << 7) + (cs ^ ((r & 7) << 3));
}

__device__ __forceinline__ unsigned asu(float x) { return __float_as_uint(x); }
__device__ __forceinline__ float asf(unsigned u) { return __uint_as_float(u); }

// pack 2 floats -> one word of 2 bf16, round-to-nearest-even (for B: zero-mean error)
__device__ __forceinline__ unsigned pk_rne(float a, float b) {
    unsigned ua = asu(a), ub = asu(b);
    ua += 0x7fffu + ((ua >> 16) & 1u);
    ub += 0x7fffu + ((ub >> 16) & 1u);
    return (ua >> 16) | (ub & 0xffff0000u);
}
// pack 2 floats -> one word of 2 bf16 (truncation; used with residual for alpha)
__device__ __forceinline__ unsigned pk_hi(float v0, float v1) {
    return (asu(v0) >> 16) | (asu(v1) & 0xffff0000u);
}
// truncation residual: x - bf16_trunc(x)
__device__ __forceinline__ float resid(float x) {
    return x - asf(asu(x) & 0xffff0000u);
}

// Fused GAT attention, 32-row tiles, single-bf16 (RNE) B + hi/lo alpha.
// grid = 256: t = bid & 63, ib = bid >> 6 (32 output rows). 512 thr = 8 waves
// (2/SIMD). LDS ~57 KB. Wave tile = 16 rows x 32 cols.
// __launch_bounds__(512,2) -> 256-VGPR cap (no spill).
__global__ __launch_bounds__(512, 2) void gat_fused(
    const float* __restrict__ A, const float* __restrict__ W,
    const float* __restrict__ b, float* __restrict__ out)
{
    __shared__ unsigned short Ah_s[NN * NN];   // bf16 RNE of A[t,f,j]   (32 KB)
    __shared__ unsigned short ah_s[32 * NN];   // bf16 hi of alpha       (8 KB)
    __shared__ unsigned short al_s[32 * NN];   // bf16 lo residual       (8 KB)
    __shared__ float part1_s[8 * NN];          // per-wave s1 partials   (4 KB)
    __shared__ float part2_s[8 * NN];          // per-wave s2 partials   (4 KB)
    __shared__ float s1_s[NN], s2_s[NN];       // 1 KB

    const int tid  = threadIdx.x;
    const int lane = tid & 63;
    const int wid  = tid >> 6;
    const int t    = blockIdx.x & 63;
    const int i0   = (blockIdx.x >> 6) << 5;   // 32-row tile
    const float* At = A + (size_t)t * NN * NN;

    // ---- stage A[t] -> bf16 (RNE) LDS; fused fp32 s1/s2 partial sums ----
    {
        const float4* A4 = reinterpret_cast<const float4*>(At);
        float p1[4] = {0,0,0,0}, p2[4] = {0,0,0,0};
        #pragma unroll
        for (int it = 0; it < 8; ++it) {
            int e4 = it * 512 + tid;          // float4 index 0..4095, coalesced
            int f  = e4 >> 5;                 // A row (k of s1/s2)
            int cs = (e4 & 31) << 2;          // column
            float4 v = A4[e4];
            float w1 = W[f], w2 = W[NN + f];  // wave-uniform broadcast loads
            p1[0] += w1 * v.x; p1[1] += w1 * v.y; p1[2] += w1 * v.z; p1[3] += w1 * v.w;
            p2[0] += w2 * v.x; p2[1] += w2 * v.y; p2[2] += w2 * v.z; p2[3] += w2 * v.w;
            uint2 hv;
            hv.x = pk_rne(v.x, v.y);
            hv.y = pk_rne(v.z, v.w);
            *reinterpret_cast<uint2*>(&Ah_s[SWZ(f, cs)]) = hv;
        }
        // lane l and l^32 covered disjoint row sets of the same columns
        #pragma unroll
        for (int q = 0; q < 4; ++q) {
            p1[q] += __shfl_xor(p1[q], 32);
            p2[q] += __shfl_xor(p2[q], 32);
        }
        if (lane < 32) {                      // col = lane*4+q
            float4 v1 = { p1[0], p1[1], p1[2], p1[3] };
            float4 v2 = { p2[0], p2[1], p2[2], p2[3] };
            *reinterpret_cast<float4*>(&part1_s[wid * NN + lane * 4]) = v1;
            *reinterpret_cast<float4*>(&part2_s[wid * NN + lane * 4]) = v2;
        }
    }
    __syncthreads();

    // ---- final s1/s2 reduce over the 8 wave partials ----
    if (tid < NN) {
        float s = b[0];
        #pragma unroll
        for (int w = 0; w < 8; ++w) s += part1_s[w * NN + tid];
        s1_s[tid] = s;
    } else if (tid < 2 * NN) {
        int c = tid - NN;
        float s = 0.f;
        #pragma unroll
        for (int w = 0; w < 8; ++w) s += part2_s[w * NN + c];
        s2_s[c] = s;
    }
    __syncthreads();

    // ---- shared softmax for rows i0..i0+31 (16 lanes/row, 8 cols/lane) ----
    {
        int rr = tid >> 4;                    // 0..31 local row
        int jj = tid & 15;                    // cols jj*8 .. jj*8+7
        float s1v = s1_s[i0 + rr];
        float4 sa = *reinterpret_cast<const float4*>(&s2_s[jj * 8]);
        float4 sb = *reinterpret_cast<const float4*>(&s2_s[jj * 8 + 4]);
        float xs[8] = { sa.x, sa.y, sa.z, sa.w, sb.x, sb.y, sb.z, sb.w };
        float ev[8];
        float m = -3.4e38f;
        #pragma unroll
        for (int c = 0; c < 8; ++c) {
            float x = s1v + xs[c];
            x = (x >= 0.f) ? x : 0.2f * x;    // leaky_relu 0.2
            ev[c] = x;
            m = fmaxf(m, x);
        }
        m = fmaxf(m, __shfl_xor(m, 1));
        m = fmaxf(m, __shfl_xor(m, 2));
        m = fmaxf(m, __shfl_xor(m, 4));
        m = fmaxf(m, __shfl_xor(m, 8));
        float s = 0.f;
        #pragma unroll
        for (int c = 0; c < 8; ++c) { ev[c] = __expf(ev[c] - m); s += ev[c]; }
        s += __shfl_xor(s, 1);
        s += __shfl_xor(s, 2);
        s += __shfl_xor(s, 4);
        s += __shfl_xor(s, 8);
        float inv = 1.0f / s;
        unsigned h[4], l[4];
        #pragma unroll
        for (int c = 0; c < 8; c += 2) {
            float v0 = ev[c] * inv, v1 = ev[c + 1] * inv;
            h[c >> 1] = pk_hi(v0, v1);
            l[c >> 1] = pk_hi(resid(v0), resid(v1));
        }
        int idx = SWZ(rr, jj * 8);
        uint4 hv = { h[0], h[1], h[2], h[3] };
        uint4 lv = { l[0], l[1], l[2], l[3] };
        *reinterpret_cast<uint4*>(&ah_s[idx]) = hv;
        *reinterpret_cast<uint4*>(&al_s[idx]) = lv;
    }
    __syncthreads();

    // ---- PV via MFMA: out rows i0+iw*16.., cols f0..f0+31 per wave ----
    {
        const int iw = wid >> 2;              // i sub-tile 0/1
        const int f0 = (wid & 3) << 5;        // wave's 32 output cols
        const int r  = lane & 15;
        const int g  = lane >> 4;             // k sub-group 0..3
        const int kg = g << 3;
        const int arow = (iw << 4) + r;       // alpha local row

        f32x4 acc0 = {0.f,0.f,0.f,0.f}, acc1 = {0.f,0.f,0.f,0.f};
        #pragma unroll
        for (int k0 = 0; k0 < 4; ++k0) {
            int c = k0 * 32 + kg;
            short8 ahk = *reinterpret_cast<const short8*>(&ah_s[SWZ(arow, c)]);
            short8 alk = *reinterpret_cast<const short8*>(&al_s[SWZ(arow, c)]);
            short8 bh0 = *reinterpret_cast<const short8*>(&Ah_s[SWZ(f0 + r, c)]);
            short8 bh1 = *reinterpret_cast<const short8*>(&Ah_s[SWZ(f0 + 16 + r, c)]);
            acc0 = __builtin_amdgcn_mfma_f32_16x16x32_bf16(ahk, bh0, acc0, 0, 0, 0);
            acc1 = __builtin_amdgcn_mfma_f32_16x16x32_bf16(ahk, bh1, acc1, 0, 0, 0);
            acc0 = __builtin_amdgcn_mfma_f32_16x16x32_bf16(alk, bh0, acc0, 0, 0, 0);
            acc1 = __builtin_amdgcn_mfma_f32_16x16x32_bf16(alk, bh1, acc1, 0, 0, 0);
        }

        // C/D: col = lane&15 (f), row = g*4 + q (i)
        float* outt = out + (size_t)t * NN * NN
                    + (size_t)(i0 + (iw << 4) + (g << 2)) * NN;
        #pragma unroll
        for (int q = 0; q < 4; ++q) {
            outt[q * NN + f0 + r]      = acc0[q];
            outt[q * NN + f0 + 16 + r] = acc1[q];
        }
    }
}

extern "C" void kernel_launch(void* const* d_in, const int* in_sizes, int n_in,
                              void* d_out, int out_size, void* d_ws, size_t ws_size,
                              hipStream_t stream) {
    const float* A = (const float*)d_in[0];
    const float* W = (const float*)d_in[1];
    const float* b = (const float*)d_in[2];
    float* out = (float*)d_out;
    gat_fused<<<dim3(256), dim3(512), 0, stream>>>(A, W, b, out);
}